// Round 8
// baseline (217.950 us; speedup 1.0000x reference)
//
#include <hip/hip_runtime.h>
#include <hip/hip_bf16.h>

#define N_TAG 128
#define T_LEN 512
#define START_TAG 126
#define STOP_TAG 127
#define PADJ 136  // bf16 elems per u-row: 272B stride, 16B-aligned

typedef __attribute__((ext_vector_type(8))) __bf16 bf16x8;
typedef __attribute__((ext_vector_type(4))) __bf16 bf16x4;
typedef __attribute__((ext_vector_type(4))) float f32x4;

// Exp-space CRF forward DP via MFMA. 2 batches/block, 256 blocks (1/CU).
// Identical math/layout to round 7 (passed, absmax 0). One change: the
// per-step __syncthreads() -> raw `s_waitcnt lgkmcnt(0); s_barrier`.
// Rationale: cross-wave data is LDS-only; __syncthreads' vmcnt(0) drain
// was killing the 8-step feat prefetch (barrier-drain stall, ~800cy/step).
// Counted vmcnt on feat-register uses now keeps global loads in flight
// across barriers (T3/T4 mechanism from the 8-phase GEMM template).
#define BAR() asm volatile("s_waitcnt lgkmcnt(0)\n\ts_barrier" ::: "memory")

__global__ __attribute__((amdgpu_flat_work_group_size(256, 256),
                          amdgpu_waves_per_eu(1, 1)))
void crf_mfma_kernel(const float* __restrict__ feats,
                     const float* __restrict__ trans,
                     const int* __restrict__ tags,
                     float* __restrict__ out, int T) {
  const int tid = threadIdx.x;
  const int w = tid >> 6;    // wave: owns tag rows [32w, 32w+32)
  const int lane = tid & 63;
  const int n = lane & 15;   // batch column
  const int g = lane >> 4;   // lane group (k-slot / row-group)
  const int bbase = blockIdx.x * 2;
  const int nn = n & 1;

  __shared__ __align__(16) __bf16 u_lds[2][16 * PADJ];
  __shared__ __align__(16) float red_lds[16][4];
  __shared__ float gold_lds[4];

  // ---- init u0 = one-hot(START) for all 16 columns ----
  for (int idx = tid; idx < 16 * PADJ; idx += 256)
    u_lds[0][idx] = (__bf16)(((idx % PADJ) == START_TAG) ? 1.0f : 0.0f);

  // ---- A-frags: a{m}[kk] lane holds E[32w+16m+n][32kk+8g+j], j=0..7 ----
  bf16x8 a0[4], a1[4];
#pragma unroll
  for (int kk = 0; kk < 4; ++kk) {
    {
      const float* p = trans + (size_t)(32 * w + n) * N_TAG + 32 * kk + 8 * g;
      f32x4 x = *(const f32x4*)(p);
      f32x4 y = *(const f32x4*)(p + 4);
      bf16x8 v;
      v[0] = (__bf16)__expf(x[0]); v[1] = (__bf16)__expf(x[1]);
      v[2] = (__bf16)__expf(x[2]); v[3] = (__bf16)__expf(x[3]);
      v[4] = (__bf16)__expf(y[0]); v[5] = (__bf16)__expf(y[1]);
      v[6] = (__bf16)__expf(y[2]); v[7] = (__bf16)__expf(y[3]);
      a0[kk] = v;
    }
    {
      const float* p = trans + (size_t)(32 * w + 16 + n) * N_TAG + 32 * kk + 8 * g;
      f32x4 x = *(const f32x4*)(p);
      f32x4 y = *(const f32x4*)(p + 4);
      bf16x8 v;
      v[0] = (__bf16)__expf(x[0]); v[1] = (__bf16)__expf(x[1]);
      v[2] = (__bf16)__expf(x[2]); v[3] = (__bf16)__expf(x[3]);
      v[4] = (__bf16)__expf(y[0]); v[5] = (__bf16)__expf(y[1]);
      v[6] = (__bf16)__expf(y[2]); v[7] = (__bf16)__expf(y[3]);
      a1[kk] = v;
    }
  }
  __syncthreads();

  const float* fbase =
      feats + (size_t)(bbase + nn) * T * N_TAG + 32 * w + 4 * g;

  f32x4 up0, up1;
  float logZ = 0.0f;

#define LOADG(D0_, D1_, T_)                           \
  do {                                                \
    const float* p_ = fbase + (size_t)(T_) * N_TAG;   \
    D0_ = *(const f32x4*)(p_);                        \
    D1_ = *(const f32x4*)(p_ + 16);                   \
  } while (0)

#define STEP(PAR_, F0_, F1_, DOREN_)                                         \
  do {                                                                       \
    const __bf16* ub_ = u_lds[PAR_];                                         \
    bf16x8 b0_ = *(const bf16x8*)(ub_ + n * PADJ + 8 * g);                   \
    bf16x8 b1_ = *(const bf16x8*)(ub_ + n * PADJ + 32 + 8 * g);              \
    bf16x8 b2_ = *(const bf16x8*)(ub_ + n * PADJ + 64 + 8 * g);              \
    bf16x8 b3_ = *(const bf16x8*)(ub_ + n * PADJ + 96 + 8 * g);              \
    f32x4 acc0_ = {0.f, 0.f, 0.f, 0.f};                                      \
    f32x4 acc1_ = {0.f, 0.f, 0.f, 0.f};                                      \
    acc0_ = __builtin_amdgcn_mfma_f32_16x16x32_bf16(a0[0], b0_, acc0_, 0, 0, 0); \
    acc1_ = __builtin_amdgcn_mfma_f32_16x16x32_bf16(a1[0], b0_, acc1_, 0, 0, 0); \
    acc0_ = __builtin_amdgcn_mfma_f32_16x16x32_bf16(a0[1], b1_, acc0_, 0, 0, 0); \
    acc1_ = __builtin_amdgcn_mfma_f32_16x16x32_bf16(a1[1], b1_, acc1_, 0, 0, 0); \
    acc0_ = __builtin_amdgcn_mfma_f32_16x16x32_bf16(a0[2], b2_, acc0_, 0, 0, 0); \
    acc1_ = __builtin_amdgcn_mfma_f32_16x16x32_bf16(a1[2], b2_, acc1_, 0, 0, 0); \
    acc0_ = __builtin_amdgcn_mfma_f32_16x16x32_bf16(a0[3], b3_, acc0_, 0, 0, 0); \
    acc1_ = __builtin_amdgcn_mfma_f32_16x16x32_bf16(a1[3], b3_, acc1_, 0, 0, 0); \
    up0[0] = acc0_[0] * __expf(F0_[0]); up0[1] = acc0_[1] * __expf(F0_[1]);  \
    up0[2] = acc0_[2] * __expf(F0_[2]); up0[3] = acc0_[3] * __expf(F0_[3]);  \
    up1[0] = acc1_[0] * __expf(F1_[0]); up1[1] = acc1_[1] * __expf(F1_[1]);  \
    up1[2] = acc1_[2] * __expf(F1_[2]); up1[3] = acc1_[3] * __expf(F1_[3]);  \
    if (DOREN_) {                                                            \
      float mx_ = fmaxf(fmaxf(fmaxf(up0[0], up0[1]), fmaxf(up0[2], up0[3])), \
                        fmaxf(fmaxf(up1[0], up1[1]), fmaxf(up1[2], up1[3]))); \
      mx_ = fmaxf(mx_, __shfl_xor(mx_, 16));                                 \
      mx_ = fmaxf(mx_, __shfl_xor(mx_, 32));                                 \
      if (g == 0) red_lds[n][w] = mx_;                                       \
      BAR();                                                                 \
      f32x4 rm_ = *(const f32x4*)red_lds[n];                                 \
      float c_ = fmaxf(fmaxf(rm_[0], rm_[1]), fmaxf(rm_[2], rm_[3]));        \
      float inv_ = 1.0f / c_;                                                \
      up0[0] *= inv_; up0[1] *= inv_; up0[2] *= inv_; up0[3] *= inv_;        \
      up1[0] *= inv_; up1[1] *= inv_; up1[2] *= inv_; up1[3] *= inv_;        \
      logZ += __logf(c_);                                                    \
    }                                                                        \
    __bf16* ud_ = u_lds[(PAR_) ^ 1];                                         \
    bf16x4 w0_, w1_;                                                         \
    w0_[0] = (__bf16)up0[0]; w0_[1] = (__bf16)up0[1];                        \
    w0_[2] = (__bf16)up0[2]; w0_[3] = (__bf16)up0[3];                        \
    w1_[0] = (__bf16)up1[0]; w1_[1] = (__bf16)up1[1];                        \
    w1_[2] = (__bf16)up1[2]; w1_[3] = (__bf16)up1[3];                        \
    *(bf16x4*)(ud_ + n * PADJ + 32 * w + 4 * g) = w0_;                       \
    *(bf16x4*)(ud_ + n * PADJ + 32 * w + 16 + 4 * g) = w1_;                  \
    BAR();                                                                   \
  } while (0)

  // prologue: prefetch steps 0..7
  f32x4 P00, P01, P10, P11, P20, P21, P30, P31;
  f32x4 Q00, Q01, Q10, Q11, Q20, Q21, Q30, Q31;
  LOADG(P00, P01, 0); LOADG(P10, P11, 1); LOADG(P20, P21, 2); LOADG(P30, P31, 3);
  LOADG(Q00, Q01, 4); LOADG(Q10, Q11, 5); LOADG(Q20, Q21, 6); LOADG(Q30, Q31, 7);

  for (int t0 = 0; t0 < T; t0 += 8) {
    STEP(0, P00, P01, false);
    STEP(1, P10, P11, false);
    STEP(0, P20, P21, false);
    STEP(1, P30, P31, true);
    if (t0 + 8 < T) {
      LOADG(P00, P01, t0 + 8);  LOADG(P10, P11, t0 + 9);
      LOADG(P20, P21, t0 + 10); LOADG(P30, P31, t0 + 11);
    }
    STEP(0, Q00, Q01, false);
    STEP(1, Q10, Q11, false);
    STEP(0, Q20, Q21, false);
    STEP(1, Q30, Q31, true);
    if (t0 + 12 < T) {
      LOADG(Q00, Q01, t0 + 12); LOADG(Q10, Q11, t0 + 13);
      LOADG(Q20, Q21, t0 + 14); LOADG(Q30, Q31, t0 + 15);
    }
  }

  // ---- forward score: log(sum_i u_i * exp(trans[STOP][i])) + logZ ----
  float term = 0.f;
#pragma unroll
  for (int r = 0; r < 4; ++r) {
    term += up0[r] * __expf(trans[STOP_TAG * N_TAG + 32 * w + 4 * g + r]);
    term += up1[r] * __expf(trans[STOP_TAG * N_TAG + 32 * w + 16 + 4 * g + r]);
  }
  term += __shfl_xor(term, 16);
  term += __shfl_xor(term, 32);
  if (g == 0) red_lds[n][w] = term;
  __syncthreads();

  // ---- gold path score (fp32 exact) ----
  const int nb = tid >> 7;  // waves 0,1 -> batch 0; waves 2,3 -> batch 1
  const int tt = tid & 127;
  const int* tg = tags + (size_t)(bbase + nb) * T;
  const float* fg = feats + (size_t)(bbase + nb) * T * N_TAG;
  float gsum = 0.f;
  for (int t = tt; t < T; t += 128) {
    int tag = tg[t];
    int prev = (t == 0) ? START_TAG : tg[t - 1];
    gsum += trans[(size_t)tag * N_TAG + prev] + fg[(size_t)t * N_TAG + tag];
    if (t == T - 1) gsum += trans[STOP_TAG * N_TAG + tag];
  }
#pragma unroll
  for (int s = 32; s; s >>= 1) gsum += __shfl_xor(gsum, s);
  if (lane == 0) gold_lds[w] = gsum;
  __syncthreads();

  if (tid < 2) {
    f32x4 rm = *(const f32x4*)red_lds[tid];
    float S = rm[0] + rm[1] + rm[2] + rm[3];
    float fwd = __logf(S) + logZ;  // lane tid: n == tid, logZ tracks col n
    float gold = gold_lds[2 * tid] + gold_lds[2 * tid + 1];
    out[bbase + tid] = fwd - gold;
  }
#undef STEP
#undef LOADG
}

extern "C" void kernel_launch(void* const* d_in, const int* in_sizes, int n_in,
                              void* d_out, int out_size, void* d_ws, size_t ws_size,
                              hipStream_t stream) {
  const float* feats = (const float*)d_in[0];
  const float* trans = (const float*)d_in[1];
  const int* tags = (const int*)d_in[2];
  float* out = (float*)d_out;
  int B = in_sizes[0] / (T_LEN * N_TAG);  // 512
  crf_mfma_kernel<<<B / 2, 256, 0, stream>>>(feats, trans, tags, out, T_LEN);
}